// Round 1
// baseline (455.311 us; speedup 1.0000x reference)
//
#include <hip/hip_runtime.h>
#include <hip/hip_bf16.h>
#include <stdint.h>
#include <math.h>

// Problem constants
#define B_    2
#define T_    2048
#define C_    2048
#define H_    16
#define D_    128
#define NQKV  6144      // 3*C
#define BT_   4096      // B*T

typedef __attribute__((ext_vector_type(8))) short  short8;   // 8 bf16 (4 VGPR) MFMA A/B frag
typedef __attribute__((ext_vector_type(4))) short  short4_;  // 4 bf16 (8B)
typedef __attribute__((ext_vector_type(4))) float  float4_;  // MFMA C/D frag

__device__ __forceinline__ unsigned short f2bf(float f) {
  union { float f; unsigned int u; } v; v.f = f;
  unsigned int u = v.u;
  return (unsigned short)((u + 0x7FFFu + ((u >> 16) & 1u)) >> 16);  // RNE
}
__device__ __forceinline__ float bf2f(unsigned short u) {
  union { unsigned int i; float f; } v; v.i = ((unsigned int)u) << 16;
  return v.f;
}

// async global->LDS, 16B per lane.  HW dest = wave-uniform base + lane*16,
// so LDS offsets must be contiguous in thread order (they are: base + tid*16).
__device__ __forceinline__ void async_cp16(const unsigned short* g, unsigned short* l) {
  __builtin_amdgcn_global_load_lds((__attribute__((address_space(1))) void*)g,
                                   (__attribute__((address_space(3))) void*)l,
                                   16, 0, 0);
}

// ---------------------------------------------------------------- fp32->bf16
__global__ __launch_bounds__(256) void cvt_bf16(const float* __restrict__ in,
                                                unsigned short* __restrict__ out, int n) {
  int i = (blockIdx.x * 256 + threadIdx.x) * 8;
  if (i + 8 > n) return;
  const float4_* p = (const float4_*)(in + i);
  float4_ a = p[0], b = p[1];
  short8 o;
  o[0] = (short)f2bf(a[0]); o[1] = (short)f2bf(a[1]);
  o[2] = (short)f2bf(a[2]); o[3] = (short)f2bf(a[3]);
  o[4] = (short)f2bf(b[0]); o[5] = (short)f2bf(b[1]);
  o[6] = (short)f2bf(b[2]); o[7] = (short)f2bf(b[3]);
  *(short8*)(out + i) = o;
}

// ------------------------------------------------------- GEMM  C = A * B^T
// A: MxK bf16 row-major, Bm: NxK bf16 row-major (B^T layout).
// 128x128 block tile, BK=64, 4 waves each 64x64 (4x4 of 16x16x32 MFMA).
// LDS tiles use XOR chunk swizzle: row of 8 16B-chunks, phys = chunk ^ (row&7)
// -> conflict-free-ish (2-way) ds_read_b128; swizzle applied on the *source*
// index of global_load_lds so the LDS side stays base + tid*16.
template <bool F32OUT>
__global__ __launch_bounds__(256) void gemm_bt(const unsigned short* __restrict__ A,
                                               const unsigned short* __restrict__ Bm,
                                               void* __restrict__ Cout,
                                               int M, int N, int K) {
  __shared__ __align__(16) unsigned short As[128 * 64];
  __shared__ __align__(16) unsigned short Bs[128 * 64];
  const int tid  = threadIdx.x;
  const int lane = tid & 63;
  const int col16 = lane & 15, quad = lane >> 4;
  const int wave = tid >> 6;
  const int wm = wave >> 1, wn = wave & 1;
  const int m0 = blockIdx.y * 128, n0 = blockIdx.x * 128;

  float4_ acc[4][4] = {};

  #pragma unroll 1
  for (int k0 = 0; k0 < K; k0 += 64) {
    __syncthreads();
    #pragma unroll
    for (int i = 0; i < 4; ++i) {
      int P   = i * 256 + tid;
      int row = P >> 3;                    // tile row 0..127
      int kc  = (P & 7) ^ (row & 7);       // logical chunk for this phys slot
      async_cp16(A  + (size_t)(m0 + row) * K + k0 + kc * 8, As + P * 8);
      async_cp16(Bm + (size_t)(n0 + row) * K + k0 + kc * 8, Bs + P * 8);
    }
    __syncthreads();
    #pragma unroll
    for (int ks = 0; ks < 2; ++ks) {
      short8 af[4], bf[4];
      #pragma unroll
      for (int i = 0; i < 4; ++i) {
        int ra = wm * 64 + i * 16 + col16;
        int ca = ((ks * 4 + quad) ^ (ra & 7)) * 8;
        af[i] = *(const short8*)(As + ra * 64 + ca);
        int rb = wn * 64 + i * 16 + col16;
        int cb = ((ks * 4 + quad) ^ (rb & 7)) * 8;
        bf[i] = *(const short8*)(Bs + rb * 64 + cb);
      }
      #pragma unroll
      for (int i = 0; i < 4; ++i)
        #pragma unroll
        for (int j = 0; j < 4; ++j)
          acc[i][j] = __builtin_amdgcn_mfma_f32_16x16x32_bf16(af[i], bf[j], acc[i][j], 0, 0, 0);
    }
  }

  // epilogue: C/D layout col=lane&15 (n), row=quad*4+reg (m)
  #pragma unroll
  for (int i = 0; i < 4; ++i) {
    int mg = m0 + wm * 64 + i * 16 + quad * 4;
    #pragma unroll
    for (int j = 0; j < 4; ++j) {
      int ng = n0 + wn * 64 + j * 16 + col16;
      #pragma unroll
      for (int r = 0; r < 4; ++r) {
        if constexpr (F32OUT)
          ((float*)Cout)[(size_t)(mg + r) * N + ng] = acc[i][j][r];
        else
          ((unsigned short*)Cout)[(size_t)(mg + r) * N + ng] = f2bf(acc[i][j][r]);
      }
    }
  }
}

// ------------------------------------------- RoPE + split + V transpose
// qkv: [BT][6144] bf16.  Outputs: q_r,k_r: [B,H,T,D] bf16;  v_t: [B,H,D,T] bf16.
// One block per (b,h, 64-token tile).
__global__ __launch_bounds__(256) void rope_split(const unsigned short* __restrict__ qkv,
                                                  const int* __restrict__ sp_ptr,
                                                  unsigned short* __restrict__ q_r,
                                                  unsigned short* __restrict__ k_r,
                                                  unsigned short* __restrict__ v_t) {
  __shared__ __align__(16) unsigned short vs[128 * 64];  // [d][t-local], chunk-swizzled
  const int blk  = blockIdx.x;           // 0..1023
  const int bh   = blk >> 5;             // 0..31
  const int tile = blk & 31;
  const int b = bh >> 4, h = bh & 15;
  const int t0 = tile * 64;
  const int tid = threadIdx.x;
  const int qidx = tid & 15;             // 16B-chunk index along D
  const int sp = sp_ptr[0];
  const bool hi = (qidx & 8) != 0;       // second half of head dim
  const float L2F = -0.20762050593046013f;  // -log2(10000)/64

  #pragma unroll
  for (int p = 0; p < 4; ++p) {
    int row = p * 16 + (tid >> 4);       // 0..63 token-local
    int tg  = t0 + row;
    size_t base = (size_t)(b * T_ + tg) * NQKV + h * D_ + qidx * 8;
    short8 q8 = *(const short8*)(qkv + base);
    short8 k8 = *(const short8*)(qkv + base + 2048);
    short8 v8 = *(const short8*)(qkv + base + 4096);
    float qf[8], kf[8], qp[8], kp[8];
    #pragma unroll
    for (int j = 0; j < 8; ++j) { qf[j] = bf2f((unsigned short)q8[j]); kf[j] = bf2f((unsigned short)k8[j]); }
    #pragma unroll
    for (int j = 0; j < 8; ++j) { qp[j] = __shfl_xor(qf[j], 8); kp[j] = __shfl_xor(kf[j], 8); }
    float pos = (float)(sp + tg);
    short8 qo, ko;
    #pragma unroll
    for (int j = 0; j < 8; ++j) {
      int d  = qidx * 8 + j;
      int fi = d & 63;
      float freq = exp2f((float)fi * L2F);
      float ang = pos * freq;
      float s, c;
      __sincosf(ang, &s, &c);   // fall back precision note: args up to ~2048
      s = sinf(ang); c = cosf(ang);  // use accurate libm versions
      float o1 = hi ? (qp[j] * s + qf[j] * c) : (qf[j] * c - qp[j] * s);
      float o2 = hi ? (kp[j] * s + kf[j] * c) : (kf[j] * c - kp[j] * s);
      qo[j] = (short)f2bf(o1);
      ko[j] = (short)f2bf(o2);
    }
    size_t ob = (size_t)(bh * T_ + tg) * D_ + qidx * 8;
    *(short8*)(q_r + ob) = qo;
    *(short8*)(k_r + ob) = ko;
    // V -> LDS transposed: element (d, row); chunk rc = row>>3, phys = rc ^ ((d>>3)&7)
    #pragma unroll
    for (int j = 0; j < 8; ++j) {
      int d  = qidx * 8 + j;
      int prc = (row >> 3) ^ ((d >> 3) & 7);
      vs[d * 64 + prc * 8 + (row & 7)] = (unsigned short)v8[j];
    }
  }
  __syncthreads();
  // write v_t rows (d-major), coalesced 64B per 2 threads
  int drow = tid >> 1;
  int half = tid & 1;
  size_t gb = (size_t)(bh * D_ + drow) * T_ + t0 + half * 32;
  #pragma unroll
  for (int c = 0; c < 4; ++c) {
    int rc  = half * 4 + c;
    int prc = rc ^ ((drow >> 3) & 7);
    *(short8*)(v_t + gb + c * 8) = *(const short8*)(vs + drow * 64 + prc * 8);
  }
}

// ------------------------------------------------------- flash attention
// Computes S^T = K·Q^T (A=K, B=Q) so stats are per-lane (col=lane&15 = q row),
// then O^T = V^T·P^T (A=V^T from v_t, B=P from LDS).  Br=Bc=64, D=128.
// Output Ob: [BT][C] bf16 (== [b,t,h*D+d]).
__global__ __launch_bounds__(256) void attn_fwd(const unsigned short* __restrict__ q_r,
                                                const unsigned short* __restrict__ k_r,
                                                const unsigned short* __restrict__ v_t,
                                                unsigned short* __restrict__ Ob) {
  __shared__ __align__(16) unsigned short Ks[64 * 128];   // [s][d] swizzled
  __shared__ __align__(16) unsigned short Vts[128 * 64];  // [d][s] swizzled
  __shared__ __align__(16) unsigned short Ps[64 * 64];    // [qrow][s] swizzled
  const int qt = blockIdx.x;     // 0..31
  const int bh = blockIdx.y;     // 0..31
  const int tid = threadIdx.x;
  const int lane = tid & 63;
  const int col16 = lane & 15, quad = lane >> 4;
  const int wave = tid >> 6;
  const int q0 = qt * 64;
  const int qg = q0 + wave * 16 + col16;     // this lane's q row
  const float scale = 0.08838834764831845f;  // 1/sqrt(128)
  const float L2E = 1.4426950408889634f;
  const float NEG_INF = -__builtin_inff();

  // Q frags (B-operand): B[k=d][n=qrow], 8 contiguous d per lane
  short8 qf[4];
  const unsigned short* qp = q_r + (size_t)(bh * T_ + qg) * D_;
  #pragma unroll
  for (int ks = 0; ks < 4; ++ks) qf[ks] = *(const short8*)(qp + ks * 32 + quad * 8);

  float4_ oacc[8] = {};
  float m_i = NEG_INF, l_i = 0.f;

  #pragma unroll 1
  for (int jt = 0; jt <= qt; ++jt) {
    __syncthreads();
    #pragma unroll
    for (int i = 0; i < 4; ++i) {
      int P = i * 256 + tid;
      int krow = P >> 4;                       // 0..63
      int kc = (P & 15) ^ (krow & 7);
      async_cp16(k_r + (size_t)(bh * T_ + jt * 64 + krow) * D_ + kc * 8, Ks + P * 8);
      int vrow = P >> 3;                       // 0..127
      int vc = (P & 7) ^ (vrow & 7);
      async_cp16(v_t + (size_t)(bh * D_ + vrow) * T_ + jt * 64 + vc * 8, Vts + P * 8);
    }
    __syncthreads();

    // S^T tiles: A = K rows (kcol), B = Q
    float4_ s[4];
    #pragma unroll
    for (int jn = 0; jn < 4; ++jn) {
      float4_ a = {};
      #pragma unroll
      for (int ks = 0; ks < 4; ++ks) {
        int kr = jn * 16 + col16;
        int ch = ((ks * 4 + quad) ^ (kr & 7)) * 8;
        short8 kfr = *(const short8*)(Ks + kr * 128 + ch);
        a = __builtin_amdgcn_mfma_f32_16x16x32_bf16(kfr, qf[ks], a, 0, 0, 0);
      }
      s[jn] = a;
    }
    // scale + causal mask (only diagonal tile needs it)
    const bool diag = (jt == qt);
    #pragma unroll
    for (int jn = 0; jn < 4; ++jn)
      #pragma unroll
      for (int r = 0; r < 4; ++r) {
        float sv = s[jn][r] * scale;
        int kg = jt * 64 + jn * 16 + quad * 4 + r;
        s[jn][r] = (diag && kg > qg) ? NEG_INF : sv;
      }
    // online softmax; stats per q row = per lane (reduce across quads)
    float rm = NEG_INF;
    #pragma unroll
    for (int jn = 0; jn < 4; ++jn)
      #pragma unroll
      for (int r = 0; r < 4; ++r) rm = fmaxf(rm, s[jn][r]);
    rm = fmaxf(rm, __shfl_xor(rm, 16));
    rm = fmaxf(rm, __shfl_xor(rm, 32));
    float m_new = fmaxf(m_i, rm);
    float alpha = exp2f((m_i - m_new) * L2E);
    float rs = 0.f;
    #pragma unroll
    for (int jn = 0; jn < 4; ++jn)
      #pragma unroll
      for (int r = 0; r < 4; ++r) {
        float pv = exp2f((s[jn][r] - m_new) * L2E);
        s[jn][r] = pv;
        rs += pv;
      }
    rs += __shfl_xor(rs, 16);
    rs += __shfl_xor(rs, 32);
    l_i = l_i * alpha + rs;
    m_i = m_new;
    #pragma unroll
    for (int dt = 0; dt < 8; ++dt) oacc[dt] *= alpha;

    // P -> LDS (row-major [qrow][s], swizzled); lane's 4 regs are contiguous cols
    int qlr = wave * 16 + col16;
    #pragma unroll
    for (int jn = 0; jn < 4; ++jn) {
      short4_ pk;
      #pragma unroll
      for (int r = 0; r < 4; ++r) pk[r] = (short)f2bf(s[jn][r]);
      int c0 = jn * 16 + quad * 4;
      int ch = (c0 >> 3) ^ (qlr & 7);
      *(short4_*)(Ps + qlr * 64 + ch * 8 + (c0 & 7)) = pk;
    }
    __builtin_amdgcn_s_waitcnt(0xC07F);  // lgkmcnt(0): wave's P writes visible to own reads

    // O^T += V^T · P^T : A = Vts (m=d), B = Ps rows (n=qrow)
    short8 pf[2];
    #pragma unroll
    for (int ks2 = 0; ks2 < 2; ++ks2) {
      int ch = ((ks2 * 4 + quad) ^ (qlr & 7)) * 8;
      pf[ks2] = *(const short8*)(Ps + qlr * 64 + ch);
    }
    #pragma unroll
    for (int dt = 0; dt < 8; ++dt)
      #pragma unroll
      for (int ks2 = 0; ks2 < 2; ++ks2) {
        int vr = dt * 16 + col16;
        int ch = ((ks2 * 4 + quad) ^ (vr & 7)) * 8;
        short8 vf = *(const short8*)(Vts + vr * 64 + ch);
        oacc[dt] = __builtin_amdgcn_mfma_f32_16x16x32_bf16(vf, pf[ks2], oacc[dt], 0, 0, 0);
      }
  }

  // epilogue: O^T C-layout col=lane&15=qrow (matches this lane's l_i), row=quad*4+r=d
  float inv_l = 1.0f / l_i;
  int b = bh >> 4, h = bh & 15;
  size_t ob = (size_t)(b * T_ + q0 + wave * 16 + col16) * C_ + h * D_;
  #pragma unroll
  for (int dt = 0; dt < 8; ++dt) {
    short4_ o4;
    #pragma unroll
    for (int r = 0; r < 4; ++r) o4[r] = (short)f2bf(oacc[dt][r] * inv_l);
    *(short4_*)(Ob + ob + dt * 16 + quad * 4) = o4;
  }
}

// ---------------------------------------------------------------- launcher
extern "C" void kernel_launch(void* const* d_in, const int* in_sizes, int n_in,
                              void* d_out, int out_size, void* d_ws, size_t ws_size,
                              hipStream_t stream) {
  const float* x     = (const float*)d_in[0];
  const float* Wqkv  = (const float*)d_in[1];
  const float* Wproj = (const float*)d_in[2];
  const int*   sp    = (const int*)d_in[3];
  float* out = (float*)d_out;

  unsigned short* ws     = (unsigned short*)d_ws;
  unsigned short* xb     = ws;                    //  8,388,608
  unsigned short* wqkvb  = xb + 8388608;          // 12,582,912
  unsigned short* wprojb = wqkvb + 12582912;      //  4,194,304
  unsigned short* qkvb   = wprojb + 4194304;      // 25,165,824
  unsigned short* q_r    = qkvb + 25165824;       //  8,388,608
  unsigned short* k_r    = q_r + 8388608;         //  8,388,608
  unsigned short* v_t    = k_r + 8388608;         //  8,388,608
  unsigned short* Obuf   = xb;                    // alias: xb dead after GEMM1

  cvt_bf16<<<8388608 / 2048, 256, 0, stream>>>(x, xb, 8388608);
  cvt_bf16<<<12582912 / 2048, 256, 0, stream>>>(Wqkv, wqkvb, 12582912);
  cvt_bf16<<<4194304 / 2048, 256, 0, stream>>>(Wproj, wprojb, 4194304);

  gemm_bt<false><<<dim3(48, 32), 256, 0, stream>>>(xb, wqkvb, (void*)qkvb, BT_, NQKV, C_);

  rope_split<<<1024, 256, 0, stream>>>(qkvb, sp, q_r, k_r, v_t);

  attn_fwd<<<dim3(32, 32), 256, 0, stream>>>(q_r, k_r, v_t, Obuf);

  gemm_bt<true><<<dim3(16, 32), 256, 0, stream>>>(Obuf, wprojb, (void*)out, BT_, C_, C_);
}

// Round 2
// 395.912 us; speedup vs baseline: 1.1500x; 1.1500x over previous
//
#include <hip/hip_runtime.h>
#include <hip/hip_bf16.h>
#include <stdint.h>
#include <math.h>

// Problem constants
#define B_    2
#define T_    2048
#define C_    2048
#define H_    16
#define D_    128
#define NQKV  6144      // 3*C
#define BT_   4096      // B*T

typedef __attribute__((ext_vector_type(8))) short  short8;   // 8 bf16 (4 VGPR) MFMA A/B frag
typedef __attribute__((ext_vector_type(4))) short  short4_;  // 4 bf16 (8B)
typedef __attribute__((ext_vector_type(4))) float  float4_;  // MFMA C/D frag

__device__ __forceinline__ unsigned short f2bf(float f) {
  union { float f; unsigned int u; } v; v.f = f;
  unsigned int u = v.u;
  return (unsigned short)((u + 0x7FFFu + ((u >> 16) & 1u)) >> 16);  // RNE
}
__device__ __forceinline__ float bf2f(unsigned short u) {
  union { unsigned int i; float f; } v; v.i = ((unsigned int)u) << 16;
  return v.f;
}
// packed fp32x2 -> bf16x2 (v_cvt_pk_bf16_f32 on gfx950 via HIP intrinsic)
__device__ __forceinline__ void pk2(short4_& dst, int idx2, float a, float b) {
  union { __hip_bfloat162 h2; struct { short x, y; } s; } u;
  u.h2 = __float22bfloat162_rn(make_float2(a, b));
  dst[idx2 * 2]     = u.s.x;
  dst[idx2 * 2 + 1] = u.s.y;
}

// async global->LDS, 16B per lane.  HW dest = wave-uniform base + lane*16,
// so LDS offsets must be contiguous in thread order (they are: base + tid*16).
__device__ __forceinline__ void async_cp16(const unsigned short* g, unsigned short* l) {
  __builtin_amdgcn_global_load_lds((__attribute__((address_space(1))) void*)g,
                                   (__attribute__((address_space(3))) void*)l,
                                   16, 0, 0);
}

// ---------------------------------------------------------------- fp32->bf16
__global__ __launch_bounds__(256) void cvt_bf16(const float* __restrict__ in,
                                                unsigned short* __restrict__ out, int n) {
  int i = (blockIdx.x * 256 + threadIdx.x) * 8;
  if (i + 8 > n) return;
  const float4_* p = (const float4_*)(in + i);
  float4_ a = p[0], b = p[1];
  short8 o;
  o[0] = (short)f2bf(a[0]); o[1] = (short)f2bf(a[1]);
  o[2] = (short)f2bf(a[2]); o[3] = (short)f2bf(a[3]);
  o[4] = (short)f2bf(b[0]); o[5] = (short)f2bf(b[1]);
  o[6] = (short)f2bf(b[2]); o[7] = (short)f2bf(b[3]);
  *(short8*)(out + i) = o;
}

// ------------------------------------------------------- GEMM  C = A * B^T
// (unchanged from round 1 — ~860 TF, m97-recipe. Frozen this round.)
template <bool F32OUT>
__global__ __launch_bounds__(256) void gemm_bt(const unsigned short* __restrict__ A,
                                               const unsigned short* __restrict__ Bm,
                                               void* __restrict__ Cout,
                                               int M, int N, int K) {
  __shared__ __align__(16) unsigned short As[128 * 64];
  __shared__ __align__(16) unsigned short Bs[128 * 64];
  const int tid  = threadIdx.x;
  const int lane = tid & 63;
  const int col16 = lane & 15, quad = lane >> 4;
  const int wave = tid >> 6;
  const int wm = wave >> 1, wn = wave & 1;
  const int m0 = blockIdx.y * 128, n0 = blockIdx.x * 128;

  float4_ acc[4][4] = {};

  #pragma unroll 1
  for (int k0 = 0; k0 < K; k0 += 64) {
    __syncthreads();
    #pragma unroll
    for (int i = 0; i < 4; ++i) {
      int P   = i * 256 + tid;
      int row = P >> 3;                    // tile row 0..127
      int kc  = (P & 7) ^ (row & 7);       // logical chunk for this phys slot
      async_cp16(A  + (size_t)(m0 + row) * K + k0 + kc * 8, As + P * 8);
      async_cp16(Bm + (size_t)(n0 + row) * K + k0 + kc * 8, Bs + P * 8);
    }
    __syncthreads();
    #pragma unroll
    for (int ks = 0; ks < 2; ++ks) {
      short8 af[4], bf[4];
      #pragma unroll
      for (int i = 0; i < 4; ++i) {
        int ra = wm * 64 + i * 16 + col16;
        int ca = ((ks * 4 + quad) ^ (ra & 7)) * 8;
        af[i] = *(const short8*)(As + ra * 64 + ca);
        int rb = wn * 64 + i * 16 + col16;
        int cb = ((ks * 4 + quad) ^ (rb & 7)) * 8;
        bf[i] = *(const short8*)(Bs + rb * 64 + cb);
      }
      #pragma unroll
      for (int i = 0; i < 4; ++i)
        #pragma unroll
        for (int j = 0; j < 4; ++j)
          acc[i][j] = __builtin_amdgcn_mfma_f32_16x16x32_bf16(af[i], bf[j], acc[i][j], 0, 0, 0);
    }
  }

  // epilogue: C/D layout col=lane&15 (n), row=quad*4+reg (m)
  #pragma unroll
  for (int i = 0; i < 4; ++i) {
    int mg = m0 + wm * 64 + i * 16 + quad * 4;
    #pragma unroll
    for (int j = 0; j < 4; ++j) {
      int ng = n0 + wn * 64 + j * 16 + col16;
      #pragma unroll
      for (int r = 0; r < 4; ++r) {
        if constexpr (F32OUT)
          ((float*)Cout)[(size_t)(mg + r) * N + ng] = acc[i][j][r];
        else
          ((unsigned short*)Cout)[(size_t)(mg + r) * N + ng] = f2bf(acc[i][j][r]);
      }
    }
  }
}

// ------------------------------------------- RoPE + split + V transpose
// qkv: [BT][6144] bf16.  Outputs: q_r (PRE-SCALED by 1/sqrt(D)*log2(e)),
// k_r: [B,H,T,D] bf16;  v_t: [B,H,D,T] bf16.
__global__ __launch_bounds__(256) void rope_split(const unsigned short* __restrict__ qkv,
                                                  const int* __restrict__ sp_ptr,
                                                  unsigned short* __restrict__ q_r,
                                                  unsigned short* __restrict__ k_r,
                                                  unsigned short* __restrict__ v_t) {
  __shared__ __align__(16) unsigned short vs[128 * 64];  // [d][t-local], chunk-swizzled
  const int blk  = blockIdx.x;           // 0..1023
  const int bh   = blk >> 5;             // 0..31
  const int tile = blk & 31;
  const int b = bh >> 4, h = bh & 15;
  const int t0 = tile * 64;
  const int tid = threadIdx.x;
  const int qidx = tid & 15;             // 16B-chunk index along D
  const int sp = sp_ptr[0];
  const bool hi = (qidx & 8) != 0;       // second half of head dim
  const float L2F = -0.20762050593046013f;  // -log2(10000)/64
  const float SCL = 0.1275174117f;          // (1/sqrt(128)) * log2(e) — folded into Q

  #pragma unroll
  for (int p = 0; p < 4; ++p) {
    int row = p * 16 + (tid >> 4);       // 0..63 token-local
    int tg  = t0 + row;
    size_t base = (size_t)(b * T_ + tg) * NQKV + h * D_ + qidx * 8;
    short8 q8 = *(const short8*)(qkv + base);
    short8 k8 = *(const short8*)(qkv + base + 2048);
    short8 v8 = *(const short8*)(qkv + base + 4096);
    float qf[8], kf[8], qp[8], kp[8];
    #pragma unroll
    for (int j = 0; j < 8; ++j) { qf[j] = bf2f((unsigned short)q8[j]); kf[j] = bf2f((unsigned short)k8[j]); }
    #pragma unroll
    for (int j = 0; j < 8; ++j) { qp[j] = __shfl_xor(qf[j], 8); kp[j] = __shfl_xor(kf[j], 8); }
    float pos = (float)(sp + tg);
    short8 qo, ko;
    #pragma unroll
    for (int j = 0; j < 8; ++j) {
      int d  = qidx * 8 + j;
      int fi = d & 63;
      float freq = exp2f((float)fi * L2F);
      float ang = pos * freq;
      float s = sinf(ang), c = cosf(ang);
      float sq = s * SCL, cq = c * SCL;
      float o1 = hi ? (qp[j] * sq + qf[j] * cq) : (qf[j] * cq - qp[j] * sq);
      float o2 = hi ? (kp[j] * s  + kf[j] * c ) : (kf[j] * c  - kp[j] * s );
      qo[j] = (short)f2bf(o1);
      ko[j] = (short)f2bf(o2);
    }
    size_t ob = (size_t)(bh * T_ + tg) * D_ + qidx * 8;
    *(short8*)(q_r + ob) = qo;
    *(short8*)(k_r + ob) = ko;
    // V -> LDS transposed: element (d, row); chunk rc = row>>3, phys = rc ^ ((d>>3)&7)
    #pragma unroll
    for (int j = 0; j < 8; ++j) {
      int d  = qidx * 8 + j;
      int prc = (row >> 3) ^ ((d >> 3) & 7);
      vs[d * 64 + prc * 8 + (row & 7)] = (unsigned short)v8[j];
    }
  }
  __syncthreads();
  // write v_t rows (d-major), coalesced
  int drow = tid >> 1;
  int half = tid & 1;
  size_t gb = (size_t)(bh * D_ + drow) * T_ + t0 + half * 32;
  #pragma unroll
  for (int c = 0; c < 4; ++c) {
    int rc  = half * 4 + c;
    int prc = rc ^ ((drow >> 3) & 7);
    *(short8*)(v_t + gb + c * 8) = *(const short8*)(vs + drow * 64 + prc * 8);
  }
}

// ------------------------------------------------------- flash attention v2
// Changes vs v1: (a) q-tile PAIRING (qt, 31-qt) -> uniform 33 iters/block,
// 512 blocks = 2/CU balanced; (b) double-buffered K/V LDS, ONE barrier/iter,
// prefetch issued right after the consuming barrier; (c) softmax in log2
// domain (Q pre-scaled by 1/sqrt(D)*log2e), diag-only mask branch, packed
// bf16 conversion. LDS = 72 KB -> 2 blocks/CU.
__global__ __launch_bounds__(256) void attn_fwd(const unsigned short* __restrict__ q_r,
                                                const unsigned short* __restrict__ k_r,
                                                const unsigned short* __restrict__ v_t,
                                                unsigned short* __restrict__ Ob) {
  __shared__ __align__(16) unsigned short Ks[2][64 * 128];   // [s][d] swizzled, dbuf
  __shared__ __align__(16) unsigned short Vts[2][128 * 64];  // [d][s] swizzled, dbuf
  __shared__ __align__(16) unsigned short Ps[64 * 64];       // [qrow][s] swizzled
  const int pairb = blockIdx.x;  // 0..15
  const int bh    = blockIdx.y;  // 0..31
  const int tid  = threadIdx.x;
  const int lane = tid & 63;
  const int col16 = lane & 15, quad = lane >> 4;
  const int wave = tid >> 6;
  const float NEG_INF = -__builtin_inff();
  const int b = bh >> 4, h = bh & 15;
  const int qlr = wave * 16 + col16;   // this lane's q row within the 64-tile

  #pragma unroll 1
  for (int half = 0; half < 2; ++half) {
    const int qt = half ? (31 - pairb) : pairb;
    const int q0 = qt * 64;

    // Q frags (B-operand): B[k=d][n=qrow], 8 contiguous d per lane (pre-scaled)
    short8 qf[4];
    const unsigned short* qp = q_r + (size_t)(bh * T_ + q0 + qlr) * D_;
    #pragma unroll
    for (int ks = 0; ks < 4; ++ks) qf[ks] = *(const short8*)(qp + ks * 32 + quad * 8);

    float4_ oacc[8] = {};
    float m_i = NEG_INF, l_i = 0.f;

    __syncthreads();   // WAR: prior half's reads of buf0 complete before restage

    // stage tile jt into buffer buf
    const unsigned short* kbase = k_r + (size_t)bh * T_ * D_;
    const unsigned short* vbase = v_t + (size_t)bh * D_ * T_;
    #define STAGE(JT, BUF)                                                        \
      {                                                                           \
        const unsigned short* kb = kbase + (size_t)(JT) * 64 * D_;                \
        const unsigned short* vb = vbase + (size_t)(JT) * 64;                     \
        unsigned short* kd = &Ks[(BUF)][0];                                       \
        unsigned short* vd = &Vts[(BUF)][0];                                      \
        _Pragma("unroll")                                                         \
        for (int i = 0; i < 4; ++i) {                                             \
          int P = i * 256 + tid;                                                  \
          int krow = P >> 4, kc = (P & 15) ^ (krow & 7);                          \
          async_cp16(kb + krow * D_ + kc * 8, kd + P * 8);                        \
          int vrow = P >> 3, vc = (P & 7) ^ (vrow & 7);                           \
          async_cp16(vb + (size_t)vrow * T_ + vc * 8, vd + P * 8);                \
        }                                                                         \
      }

    STAGE(0, 0);

    #pragma unroll 1
    for (int jt = 0; jt <= qt; ++jt) {
      __syncthreads();                    // drains vmcnt: tile jt landed; prior reads done
      if (jt < qt) STAGE(jt + 1, (jt + 1) & 1);
      const unsigned short* KsB  = &Ks[jt & 1][0];
      const unsigned short* VtsB = &Vts[jt & 1][0];

      // S^T tiles: A = K rows, B = Q  (values already in log2-softmax domain)
      float4_ s[4];
      #pragma unroll
      for (int jn = 0; jn < 4; ++jn) {
        float4_ a = {};
        #pragma unroll
        for (int ks = 0; ks < 4; ++ks) {
          int kr = jn * 16 + col16;
          int ch = ((ks * 4 + quad) ^ (kr & 7)) * 8;
          short8 kfr = *(const short8*)(KsB + kr * 128 + ch);
          a = __builtin_amdgcn_mfma_f32_16x16x32_bf16(kfr, qf[ks], a, 0, 0, 0);
        }
        s[jn] = a;
      }
      if (jt == qt) {  // wave-uniform diag-mask branch
        #pragma unroll
        for (int jn = 0; jn < 4; ++jn)
          #pragma unroll
          for (int r = 0; r < 4; ++r)
            if (jn * 16 + quad * 4 + r > qlr) s[jn][r] = NEG_INF;
      }
      // online softmax (log2 domain); stats per q row = per lane
      float rm = NEG_INF;
      #pragma unroll
      for (int jn = 0; jn < 4; ++jn)
        #pragma unroll
        for (int r = 0; r < 4; ++r) rm = fmaxf(rm, s[jn][r]);
      rm = fmaxf(rm, __shfl_xor(rm, 16));
      rm = fmaxf(rm, __shfl_xor(rm, 32));
      float m_new = fmaxf(m_i, rm);
      float alpha = exp2f(m_i - m_new);
      float rs = 0.f;
      #pragma unroll
      for (int jn = 0; jn < 4; ++jn)
        #pragma unroll
        for (int r = 0; r < 4; ++r) {
          float pv = exp2f(s[jn][r] - m_new);
          s[jn][r] = pv;
          rs += pv;
        }
      rs += __shfl_xor(rs, 16);
      rs += __shfl_xor(rs, 32);
      l_i = l_i * alpha + rs;
      m_i = m_new;
      #pragma unroll
      for (int dt = 0; dt < 8; ++dt) oacc[dt] *= alpha;

      // P -> LDS (wave-private rows), packed bf16
      #pragma unroll
      for (int jn = 0; jn < 4; ++jn) {
        short4_ pkv;
        pk2(pkv, 0, s[jn][0], s[jn][1]);
        pk2(pkv, 1, s[jn][2], s[jn][3]);
        int c0 = jn * 16 + quad * 4;
        int ch = (c0 >> 3) ^ (qlr & 7);
        *(short4_*)(Ps + qlr * 64 + ch * 8 + (c0 & 7)) = pkv;
      }
      __builtin_amdgcn_s_waitcnt(0xC07F);  // lgkmcnt(0): own P writes -> own reads

      // O^T += V^T · P^T : A = Vts (m=d), B = Ps rows (n=qrow)
      short8 pf[2];
      #pragma unroll
      for (int ks2 = 0; ks2 < 2; ++ks2) {
        int ch = ((ks2 * 4 + quad) ^ (qlr & 7)) * 8;
        pf[ks2] = *(const short8*)(Ps + qlr * 64 + ch);
      }
      #pragma unroll
      for (int dt = 0; dt < 8; ++dt)
        #pragma unroll
        for (int ks2 = 0; ks2 < 2; ++ks2) {
          int vr = dt * 16 + col16;
          int ch = ((ks2 * 4 + quad) ^ (vr & 7)) * 8;
          short8 vf = *(const short8*)(VtsB + vr * 64 + ch);
          oacc[dt] = __builtin_amdgcn_mfma_f32_16x16x32_bf16(vf, pf[ks2], oacc[dt], 0, 0, 0);
        }
    }

    // epilogue: O^T C-layout col=lane&15=qrow, row=quad*4+r=d
    float inv_l = 1.0f / l_i;
    size_t ob = (size_t)(b * T_ + q0 + qlr) * C_ + h * D_;
    #pragma unroll
    for (int dt = 0; dt < 8; ++dt) {
      short4_ o4;
      pk2(o4, 0, oacc[dt][0] * inv_l, oacc[dt][1] * inv_l);
      pk2(o4, 1, oacc[dt][2] * inv_l, oacc[dt][3] * inv_l);
      *(short4_*)(Ob + ob + dt * 16 + quad * 4) = o4;
    }
    #undef STAGE
  }
}

// ---------------------------------------------------------------- launcher
extern "C" void kernel_launch(void* const* d_in, const int* in_sizes, int n_in,
                              void* d_out, int out_size, void* d_ws, size_t ws_size,
                              hipStream_t stream) {
  const float* x     = (const float*)d_in[0];
  const float* Wqkv  = (const float*)d_in[1];
  const float* Wproj = (const float*)d_in[2];
  const int*   sp    = (const int*)d_in[3];
  float* out = (float*)d_out;

  unsigned short* ws     = (unsigned short*)d_ws;
  unsigned short* xb     = ws;                    //  8,388,608
  unsigned short* wqkvb  = xb + 8388608;          // 12,582,912
  unsigned short* wprojb = wqkvb + 12582912;      //  4,194,304
  unsigned short* qkvb   = wprojb + 4194304;      // 25,165,824
  unsigned short* q_r    = qkvb + 25165824;       //  8,388,608
  unsigned short* k_r    = q_r + 8388608;         //  8,388,608
  unsigned short* v_t    = k_r + 8388608;         //  8,388,608
  unsigned short* Obuf   = xb;                    // alias: xb dead after GEMM1

  cvt_bf16<<<8388608 / 2048, 256, 0, stream>>>(x, xb, 8388608);
  cvt_bf16<<<12582912 / 2048, 256, 0, stream>>>(Wqkv, wqkvb, 12582912);
  cvt_bf16<<<4194304 / 2048, 256, 0, stream>>>(Wproj, wprojb, 4194304);

  gemm_bt<false><<<dim3(48, 32), 256, 0, stream>>>(xb, wqkvb, (void*)qkvb, BT_, NQKV, C_);

  rope_split<<<1024, 256, 0, stream>>>(qkvb, sp, q_r, k_r, v_t);

  attn_fwd<<<dim3(16, 32), 256, 0, stream>>>(q_r, k_r, v_t, Obuf);

  gemm_bt<true><<<dim3(16, 32), 256, 0, stream>>>(Obuf, wprojb, (void*)out, BT_, C_, C_);
}

// Round 3
// 384.176 us; speedup vs baseline: 1.1852x; 1.0305x over previous
//
#include <hip/hip_runtime.h>
#include <hip/hip_bf16.h>
#include <stdint.h>
#include <math.h>

// Problem constants
#define B_    2
#define T_    2048
#define C_    2048
#define H_    16
#define D_    128
#define NQKV  6144      // 3*C
#define BT_   4096      // B*T

typedef __attribute__((ext_vector_type(8))) short  short8;   // 8 bf16 (4 VGPR) MFMA A/B frag
typedef __attribute__((ext_vector_type(4))) short  short4_;  // 4 bf16 (8B)
typedef __attribute__((ext_vector_type(4))) float  float4_;  // MFMA C/D frag

__device__ __forceinline__ unsigned short f2bf(float f) {
  union { float f; unsigned int u; } v; v.f = f;
  unsigned int u = v.u;
  return (unsigned short)((u + 0x7FFFu + ((u >> 16) & 1u)) >> 16);  // RNE
}
__device__ __forceinline__ float bf2f(unsigned short u) {
  union { unsigned int i; float f; } v; v.i = ((unsigned int)u) << 16;
  return v.f;
}
// packed fp32x2 -> bf16x2
__device__ __forceinline__ void pk2(short4_& dst, int idx2, float a, float b) {
  union { __hip_bfloat162 h2; struct { short x, y; } s; } u;
  u.h2 = __float22bfloat162_rn(make_float2(a, b));
  dst[idx2 * 2]     = u.s.x;
  dst[idx2 * 2 + 1] = u.s.y;
}

// async global->LDS, 16B per lane.  HW dest = wave-uniform base + lane*16,
// so LDS offsets must be contiguous in thread order (they are: base + tid*16).
__device__ __forceinline__ void async_cp16(const unsigned short* g, unsigned short* l) {
  __builtin_amdgcn_global_load_lds((__attribute__((address_space(1))) void*)g,
                                   (__attribute__((address_space(3))) void*)l,
                                   16, 0, 0);
}

// --------------------------------------------------- fused fp32->bf16 (all 3 inputs)
// Output regions are contiguous in ws: xb @0 (8388608), wqkvb @8388608 (12582912),
// wprojb @20971520 (4194304).  One kernel, one launch.
__global__ __launch_bounds__(256) void cvt_all(const float* __restrict__ x,
                                               const float* __restrict__ wqkv,
                                               const float* __restrict__ wproj,
                                               unsigned short* __restrict__ out) {
  int i = (blockIdx.x * 256 + threadIdx.x) * 8;   // 0 .. 25165824-8
  const float* src; int off;
  if (i < 8388608)       { src = x;     off = i; }
  else if (i < 20971520) { src = wqkv;  off = i - 8388608; }
  else                   { src = wproj; off = i - 20971520; }
  const float4_* p = (const float4_*)(src + off);
  float4_ a = p[0], b = p[1];
  short8 o;
  o[0] = (short)f2bf(a[0]); o[1] = (short)f2bf(a[1]);
  o[2] = (short)f2bf(a[2]); o[3] = (short)f2bf(a[3]);
  o[4] = (short)f2bf(b[0]); o[5] = (short)f2bf(b[1]);
  o[6] = (short)f2bf(b[2]); o[7] = (short)f2bf(b[3]);
  *(short8*)(out + i) = o;
}

// ------------------------------------------------------- GEMM  C = A * B^T
// (frozen — 906 TF, at the m97-structure plateau; SQ_LDS_BANK_CONFLICT=0)
template <bool F32OUT>
__global__ __launch_bounds__(256) void gemm_bt(const unsigned short* __restrict__ A,
                                               const unsigned short* __restrict__ Bm,
                                               void* __restrict__ Cout,
                                               int M, int N, int K) {
  __shared__ __align__(16) unsigned short As[128 * 64];
  __shared__ __align__(16) unsigned short Bs[128 * 64];
  const int tid  = threadIdx.x;
  const int lane = tid & 63;
  const int col16 = lane & 15, quad = lane >> 4;
  const int wave = tid >> 6;
  const int wm = wave >> 1, wn = wave & 1;
  const int m0 = blockIdx.y * 128, n0 = blockIdx.x * 128;

  float4_ acc[4][4] = {};

  #pragma unroll 1
  for (int k0 = 0; k0 < K; k0 += 64) {
    __syncthreads();
    #pragma unroll
    for (int i = 0; i < 4; ++i) {
      int P   = i * 256 + tid;
      int row = P >> 3;                    // tile row 0..127
      int kc  = (P & 7) ^ (row & 7);       // logical chunk for this phys slot
      async_cp16(A  + (size_t)(m0 + row) * K + k0 + kc * 8, As + P * 8);
      async_cp16(Bm + (size_t)(n0 + row) * K + k0 + kc * 8, Bs + P * 8);
    }
    __syncthreads();
    #pragma unroll
    for (int ks = 0; ks < 2; ++ks) {
      short8 af[4], bf[4];
      #pragma unroll
      for (int i = 0; i < 4; ++i) {
        int ra = wm * 64 + i * 16 + col16;
        int ca = ((ks * 4 + quad) ^ (ra & 7)) * 8;
        af[i] = *(const short8*)(As + ra * 64 + ca);
        int rb = wn * 64 + i * 16 + col16;
        int cb = ((ks * 4 + quad) ^ (rb & 7)) * 8;
        bf[i] = *(const short8*)(Bs + rb * 64 + cb);
      }
      #pragma unroll
      for (int i = 0; i < 4; ++i)
        #pragma unroll
        for (int j = 0; j < 4; ++j)
          acc[i][j] = __builtin_amdgcn_mfma_f32_16x16x32_bf16(af[i], bf[j], acc[i][j], 0, 0, 0);
    }
  }

  // epilogue: C/D layout col=lane&15 (n), row=quad*4+reg (m)
  #pragma unroll
  for (int i = 0; i < 4; ++i) {
    int mg = m0 + wm * 64 + i * 16 + quad * 4;
    #pragma unroll
    for (int j = 0; j < 4; ++j) {
      int ng = n0 + wn * 64 + j * 16 + col16;
      #pragma unroll
      for (int r = 0; r < 4; ++r) {
        if constexpr (F32OUT)
          ((float*)Cout)[(size_t)(mg + r) * N + ng] = acc[i][j][r];
        else
          ((unsigned short*)Cout)[(size_t)(mg + r) * N + ng] = f2bf(acc[i][j][r]);
      }
    }
  }
}

// ------------------------------------------- RoPE + split + V transpose (frozen)
// qkv: [BT][6144] bf16.  Outputs: q_r (PRE-SCALED by 1/sqrt(D)*log2(e)),
// k_r: [B,H,T,D] bf16;  v_t: [B,H,D,T] bf16.
__global__ __launch_bounds__(256) void rope_split(const unsigned short* __restrict__ qkv,
                                                  const int* __restrict__ sp_ptr,
                                                  unsigned short* __restrict__ q_r,
                                                  unsigned short* __restrict__ k_r,
                                                  unsigned short* __restrict__ v_t) {
  __shared__ __align__(16) unsigned short vs[128 * 64];  // [d][t-local], chunk-swizzled
  const int blk  = blockIdx.x;           // 0..1023
  const int bh   = blk >> 5;             // 0..31
  const int tile = blk & 31;
  const int b = bh >> 4, h = bh & 15;
  const int t0 = tile * 64;
  const int tid = threadIdx.x;
  const int qidx = tid & 15;             // 16B-chunk index along D
  const int sp = sp_ptr[0];
  const bool hi = (qidx & 8) != 0;       // second half of head dim
  const float L2F = -0.20762050593046013f;  // -log2(10000)/64
  const float SCL = 0.1275174117f;          // (1/sqrt(128)) * log2(e) — folded into Q

  #pragma unroll
  for (int p = 0; p < 4; ++p) {
    int row = p * 16 + (tid >> 4);       // 0..63 token-local
    int tg  = t0 + row;
    size_t base = (size_t)(b * T_ + tg) * NQKV + h * D_ + qidx * 8;
    short8 q8 = *(const short8*)(qkv + base);
    short8 k8 = *(const short8*)(qkv + base + 2048);
    short8 v8 = *(const short8*)(qkv + base + 4096);
    float qf[8], kf[8], qp[8], kp[8];
    #pragma unroll
    for (int j = 0; j < 8; ++j) { qf[j] = bf2f((unsigned short)q8[j]); kf[j] = bf2f((unsigned short)k8[j]); }
    #pragma unroll
    for (int j = 0; j < 8; ++j) { qp[j] = __shfl_xor(qf[j], 8); kp[j] = __shfl_xor(kf[j], 8); }
    float pos = (float)(sp + tg);
    short8 qo, ko;
    #pragma unroll
    for (int j = 0; j < 8; ++j) {
      int d  = qidx * 8 + j;
      int fi = d & 63;
      float freq = exp2f((float)fi * L2F);
      float ang = pos * freq;
      float s = sinf(ang), c = cosf(ang);
      float sq = s * SCL, cq = c * SCL;
      float o1 = hi ? (qp[j] * sq + qf[j] * cq) : (qf[j] * cq - qp[j] * sq);
      float o2 = hi ? (kp[j] * s  + kf[j] * c ) : (kf[j] * c  - kp[j] * s );
      qo[j] = (short)f2bf(o1);
      ko[j] = (short)f2bf(o2);
    }
    size_t ob = (size_t)(bh * T_ + tg) * D_ + qidx * 8;
    *(short8*)(q_r + ob) = qo;
    *(short8*)(k_r + ob) = ko;
    // V -> LDS transposed: element (d, row); chunk rc = row>>3, phys = rc ^ ((d>>3)&7)
    #pragma unroll
    for (int j = 0; j < 8; ++j) {
      int d  = qidx * 8 + j;
      int prc = (row >> 3) ^ ((d >> 3) & 7);
      vs[d * 64 + prc * 8 + (row & 7)] = (unsigned short)v8[j];
    }
  }
  __syncthreads();
  // write v_t rows (d-major), coalesced
  int drow = tid >> 1;
  int half = tid & 1;
  size_t gb = (size_t)(bh * D_ + drow) * T_ + t0 + half * 32;
  #pragma unroll
  for (int c = 0; c < 4; ++c) {
    int rc  = half * 4 + c;
    int prc = rc ^ ((drow >> 3) & 7);
    *(short8*)(v_t + gb + c * 8) = *(const short8*)(vs + drow * 64 + prc * 8);
  }
}

// ------------------------------------------------------- flash attention v3
// Changes vs v2: Br 64 -> 128 (512-thread blocks, 8 waves x 16 q-rows; per-wave
// code unchanged).  Halves K/V staging traffic (~540 -> ~270 MB) and barriers
// per MFMA.  Pairing (qt, 15-qt) -> 256 blocks x uniform 34 iters = 1 block/CU,
// zero tail.  bh in low 5 bits of blockIdx -> XCD = bh%8 -> 4 heads (4 MB K/V)
// per XCD L2.  Wave-uniform dead-tile skip on the upper diagonal tile.
// LDS = 32 (K dbuf) + 32 (V dbuf) + 16 (Ps) = 80 KB.
__global__ __launch_bounds__(512) void attn_fwd(const unsigned short* __restrict__ q_r,
                                                const unsigned short* __restrict__ k_r,
                                                const unsigned short* __restrict__ v_t,
                                                unsigned short* __restrict__ Ob) {
  __shared__ __align__(16) unsigned short Ks[2][64 * 128];   // [s][d] swizzled, dbuf
  __shared__ __align__(16) unsigned short Vts[2][128 * 64];  // [d][s] swizzled, dbuf
  __shared__ __align__(16) unsigned short Ps[128 * 64];      // [qrow][s] swizzled
  const int pairb = blockIdx.x >> 5;   // 0..7
  const int bh    = blockIdx.x & 31;   // low bits -> XCD locality by head
  const int tid  = threadIdx.x;
  const int lane = tid & 63;
  const int col16 = lane & 15, quad = lane >> 4;
  const int wave = tid >> 6;           // 0..7
  const float NEG_INF = -__builtin_inff();
  const int b = bh >> 4, h = bh & 15;
  const int qlr = wave * 16 + col16;   // this lane's q row within the 128-tile

  #pragma unroll 1
  for (int half = 0; half < 2; ++half) {
    const int qt = half ? (15 - pairb) : pairb;   // 128-row q tile index
    const int q0 = qt * 128;
    const int njt = 2 * qt + 2;                   // 64-row kv tiles

    // Q frags (B-operand): B[k=d][n=qrow], 8 contiguous d per lane (pre-scaled)
    short8 qf[4];
    const unsigned short* qp = q_r + (size_t)(bh * T_ + q0 + qlr) * D_;
    #pragma unroll
    for (int ks = 0; ks < 4; ++ks) qf[ks] = *(const short8*)(qp + ks * 32 + quad * 8);

    float4_ oacc[8] = {};
    float m_i = NEG_INF, l_i = 0.f;

    __syncthreads();   // WAR: prior half's reads complete before restage

    const unsigned short* kbase = k_r + (size_t)bh * T_ * D_;
    const unsigned short* vbase = v_t + (size_t)bh * D_ * T_;
    #define STAGE(JT, BUF)                                                        \
      {                                                                           \
        const unsigned short* kb = kbase + (size_t)(JT) * 64 * D_;                \
        const unsigned short* vb = vbase + (size_t)(JT) * 64;                     \
        unsigned short* kd = &Ks[(BUF)][0];                                       \
        unsigned short* vd = &Vts[(BUF)][0];                                      \
        _Pragma("unroll")                                                         \
        for (int i = 0; i < 2; ++i) {                                             \
          int P = i * 512 + tid;                                                  \
          int krow = P >> 4, kc = (P & 15) ^ (krow & 7);                          \
          async_cp16(kb + krow * D_ + kc * 8, kd + P * 8);                        \
          int vrow = P >> 3, vc = (P & 7) ^ (vrow & 7);                           \
          async_cp16(vb + (size_t)vrow * T_ + vc * 8, vd + P * 8);                \
        }                                                                         \
      }

    STAGE(0, 0);

    #pragma unroll 1
    for (int jt = 0; jt < njt; ++jt) {
      __syncthreads();                    // tile jt landed; prior reads done
      if (jt + 1 < njt) STAGE(jt + 1, (jt + 1) & 1);

      // wave-uniform skip: this wave's 16 q-rows all above (before) this kv tile
      if (jt * 64 > q0 + wave * 16 + 15) continue;

      const unsigned short* KsB  = &Ks[jt & 1][0];
      const unsigned short* VtsB = &Vts[jt & 1][0];

      // S^T tiles: A = K rows, B = Q  (values already in log2-softmax domain)
      float4_ s[4];
      #pragma unroll
      for (int jn = 0; jn < 4; ++jn) {
        float4_ a = {};
        #pragma unroll
        for (int ks = 0; ks < 4; ++ks) {
          int kr = jn * 16 + col16;
          int ch = ((ks * 4 + quad) ^ (kr & 7)) * 8;
          short8 kfr = *(const short8*)(KsB + kr * 128 + ch);
          a = __builtin_amdgcn_mfma_f32_16x16x32_bf16(kfr, qf[ks], a, 0, 0, 0);
        }
        s[jn] = a;
      }
      if (jt * 64 + 63 > q0 + wave * 16) {  // wave-uniform partial-mask branch
        #pragma unroll
        for (int jn = 0; jn < 4; ++jn)
          #pragma unroll
          for (int r = 0; r < 4; ++r)
            if (jt * 64 + jn * 16 + quad * 4 + r > q0 + qlr) s[jn][r] = NEG_INF;
      }
      // online softmax (log2 domain); stats per q row = per lane
      float rm = NEG_INF;
      #pragma unroll
      for (int jn = 0; jn < 4; ++jn)
        #pragma unroll
        for (int r = 0; r < 4; ++r) rm = fmaxf(rm, s[jn][r]);
      rm = fmaxf(rm, __shfl_xor(rm, 16));
      rm = fmaxf(rm, __shfl_xor(rm, 32));
      float m_new = fmaxf(m_i, rm);
      float alpha = exp2f(m_i - m_new);
      float rs = 0.f;
      #pragma unroll
      for (int jn = 0; jn < 4; ++jn)
        #pragma unroll
        for (int r = 0; r < 4; ++r) {
          float pv = exp2f(s[jn][r] - m_new);
          s[jn][r] = pv;
          rs += pv;
        }
      rs += __shfl_xor(rs, 16);
      rs += __shfl_xor(rs, 32);
      l_i = l_i * alpha + rs;
      m_i = m_new;
      #pragma unroll
      for (int dt = 0; dt < 8; ++dt) oacc[dt] *= alpha;

      // P -> LDS (wave-private rows), packed bf16
      #pragma unroll
      for (int jn = 0; jn < 4; ++jn) {
        short4_ pkv;
        pk2(pkv, 0, s[jn][0], s[jn][1]);
        pk2(pkv, 1, s[jn][2], s[jn][3]);
        int c0 = jn * 16 + quad * 4;
        int ch = (c0 >> 3) ^ (qlr & 7);
        *(short4_*)(Ps + qlr * 64 + ch * 8 + (c0 & 7)) = pkv;
      }
      __builtin_amdgcn_s_waitcnt(0xC07F);  // lgkmcnt(0): own P writes -> own reads

      // O^T += V^T · P^T : A = Vts (m=d), B = Ps rows (n=qrow)
      short8 pf[2];
      #pragma unroll
      for (int ks2 = 0; ks2 < 2; ++ks2) {
        int ch = ((ks2 * 4 + quad) ^ (qlr & 7)) * 8;
        pf[ks2] = *(const short8*)(Ps + qlr * 64 + ch);
      }
      #pragma unroll
      for (int dt = 0; dt < 8; ++dt)
        #pragma unroll
        for (int ks2 = 0; ks2 < 2; ++ks2) {
          int vr = dt * 16 + col16;
          int ch = ((ks2 * 4 + quad) ^ (vr & 7)) * 8;
          short8 vf = *(const short8*)(VtsB + vr * 64 + ch);
          oacc[dt] = __builtin_amdgcn_mfma_f32_16x16x32_bf16(vf, pf[ks2], oacc[dt], 0, 0, 0);
        }
    }

    // epilogue: O^T C-layout col=lane&15=qrow, row=quad*4+r=d
    float inv_l = 1.0f / l_i;
    size_t ob = (size_t)(b * T_ + q0 + qlr) * C_ + h * D_;
    #pragma unroll
    for (int dt = 0; dt < 8; ++dt) {
      short4_ o4;
      pk2(o4, 0, oacc[dt][0] * inv_l, oacc[dt][1] * inv_l);
      pk2(o4, 1, oacc[dt][2] * inv_l, oacc[dt][3] * inv_l);
      *(short4_*)(Ob + ob + dt * 16 + quad * 4) = o4;
    }
    #undef STAGE
  }
}

// ---------------------------------------------------------------- launcher
extern "C" void kernel_launch(void* const* d_in, const int* in_sizes, int n_in,
                              void* d_out, int out_size, void* d_ws, size_t ws_size,
                              hipStream_t stream) {
  const float* x     = (const float*)d_in[0];
  const float* Wqkv  = (const float*)d_in[1];
  const float* Wproj = (const float*)d_in[2];
  const int*   sp    = (const int*)d_in[3];
  float* out = (float*)d_out;

  unsigned short* ws     = (unsigned short*)d_ws;
  unsigned short* xb     = ws;                    //  8,388,608
  unsigned short* wqkvb  = xb + 8388608;          // 12,582,912
  unsigned short* wprojb = wqkvb + 12582912;      //  4,194,304
  unsigned short* qkvb   = wprojb + 4194304;      // 25,165,824
  unsigned short* q_r    = qkvb + 25165824;       //  8,388,608
  unsigned short* k_r    = q_r + 8388608;         //  8,388,608
  unsigned short* v_t    = k_r + 8388608;         //  8,388,608
  unsigned short* Obuf   = xb;                    // alias: xb dead after GEMM1

  cvt_all<<<25165824 / 2048, 256, 0, stream>>>(x, Wqkv, Wproj, ws);

  gemm_bt<false><<<dim3(48, 32), 256, 0, stream>>>(xb, wqkvb, (void*)qkvb, BT_, NQKV, C_);

  rope_split<<<1024, 256, 0, stream>>>(qkvb, sp, q_r, k_r, v_t);

  attn_fwd<<<dim3(256), 512, 0, stream>>>(q_r, k_r, v_t, Obuf);

  gemm_bt<true><<<dim3(16, 32), 256, 0, stream>>>(Obuf, wprojb, (void*)out, BT_, C_, C_);
}